// Round 3
// baseline (136.035 us; speedup 1.0000x reference)
//
#include <hip/hip_runtime.h>

#define M_NODES 100000
#define BM 64
#define NBLK ((M_NODES + BM - 1) / BM)   // 1563

typedef float  f32x4  __attribute__((ext_vector_type(4)));
typedef short  bf16x8 __attribute__((ext_vector_type(8)));

__device__ __forceinline__ unsigned short f2bf(float f) {
  union { float f; unsigned int u; } v; v.f = f;
  unsigned int u = v.u;
  return (unsigned short)((u + 0x7FFFu + ((u >> 16) & 1u)) >> 16);  // RNE
}

__device__ __forceinline__ bf16x8 cvt8(f32x4 u0, f32x4 u1) {
  union { unsigned int u[4]; bf16x8 v; } r;
  asm("v_cvt_pk_bf16_f32 %0, %1, %2" : "=v"(r.u[0]) : "v"(u0[0]), "v"(u0[1]));
  asm("v_cvt_pk_bf16_f32 %0, %1, %2" : "=v"(r.u[1]) : "v"(u0[2]), "v"(u0[3]));
  asm("v_cvt_pk_bf16_f32 %0, %1, %2" : "=v"(r.u[2]) : "v"(u1[0]), "v"(u1[1]));
  asm("v_cvt_pk_bf16_f32 %0, %1, %2" : "=v"(r.u[3]) : "v"(u1[2]), "v"(u1[3]));
  return r.v;
}

// ---------------------------------------------------------------------------
// prep: W[k][n] f32 -> Wu[n*256+k] bf16 (transposed, B-frag-ready, L2-hot)
// ---------------------------------------------------------------------------
__global__ void prep_w(const float* __restrict__ W1, const float* __restrict__ W2,
                       unsigned short* __restrict__ U1, unsigned short* __restrict__ U2) {
  int b = blockIdx.x;                       // 512 blocks x 256 threads
  const float* W = (b < 256) ? W1 : W2;
  unsigned short* U = (b < 256) ? U1 : U2;
  int n = b & 255, k = threadIdx.x;
  U[n * 256 + k] = f2bf(W[k * 256 + n]);
}

// ---------------------------------------------------------------------------
// Fused, staging-free: out[64 x 256] = relu(X@W1+b1)@W2 + b2 per block.
// 256 threads = 4 waves, wave wc owns cols [64wc, 64wc+64) (4x4 16x16x32).
// A frags: global f32 -> cvt_pk (GEMM1) / LDS Hbuf swizzled (GEMM2).
// B frags: global bf16 from Wu images (L2-resident).
// LDS = Hbuf 32KB only; ONE barrier per block. launch_bounds(256,4):
// VGPR<=128 -> 4 blocks/CU = 16 waves/CU.
// ---------------------------------------------------------------------------
__global__ __launch_bounds__(256, 4)
void cheb_fused(const float* __restrict__ X,
                const unsigned short* __restrict__ W1u,
                const unsigned short* __restrict__ W2u,
                const float* __restrict__ b1,
                const float* __restrict__ b2,
                float* __restrict__ out)
{
  __shared__ unsigned short Hbuf[64 * 256];   // 32 KB

  const int tid  = threadIdx.x;
  const int lane = tid & 63;
  const int l15  = lane & 15;
  const int lhi  = lane >> 4;                 // 0..3 (k-slot within 32-k step)
  const int wc   = tid >> 6;                  // 0..3 (N quarter)
  const int rb   = blockIdx.x;

  f32x4 acc[4][4] = {};

  // ---- GEMM1: H = relu(X @ W1 + b1), K = 256 in 8 steps of 32 ------------
  #pragma unroll 1
  for (int kk = 0; kk < 8; ++kk) {
    const int kof = kk * 32 + lhi * 8;
    bf16x8 a[4], b[4];
    #pragma unroll
    for (int mi = 0; mi < 4; ++mi) {
      int grow = rb * BM + mi * 16 + l15;
      f32x4 u0 = {0.f, 0.f, 0.f, 0.f}, u1 = {0.f, 0.f, 0.f, 0.f};
      if (grow < M_NODES) {
        const float* p = X + (size_t)grow * 256 + kof;
        u0 = *(const f32x4*)p;
        u1 = *(const f32x4*)(p + 4);
      }
      a[mi] = cvt8(u0, u1);
    }
    #pragma unroll
    for (int ni = 0; ni < 4; ++ni) {
      int n = wc * 64 + ni * 16 + l15;
      b[ni] = *(const bf16x8*)(W1u + n * 256 + kof);
    }
    #pragma unroll
    for (int mi = 0; mi < 4; ++mi)
      #pragma unroll
      for (int ni = 0; ni < 4; ++ni)
        acc[mi][ni] = __builtin_amdgcn_mfma_f32_16x16x32_bf16(a[mi], b[ni], acc[mi][ni], 0, 0, 0);
  }

  // ---- epilogue1: bias + relu + bf16 -> Hbuf (XOR-swizzled) --------------
  {
    #pragma unroll
    for (int ni = 0; ni < 4; ++ni) {
      int k = wc * 64 + ni * 16 + l15;
      float bn = b1[k];
      #pragma unroll
      for (int mi = 0; mi < 4; ++mi)
        #pragma unroll
        for (int rg = 0; rg < 4; ++rg) {
          int r = mi * 16 + lhi * 4 + rg;
          float v = fmaxf(acc[mi][ni][rg] + bn, 0.f);
          Hbuf[r * 256 + (((k >> 3) ^ (r & 7)) << 3) + (k & 7)] = f2bf(v);
          acc[mi][ni][rg] = 0.f;
        }
    }
  }
  __syncthreads();                            // the only barrier

  // ---- GEMM2: out = H @ W2 + b2 ------------------------------------------
  #pragma unroll 1
  for (int kk = 0; kk < 8; ++kk) {
    bf16x8 a[4], b[4];
    #pragma unroll
    for (int mi = 0; mi < 4; ++mi) {
      int r = mi * 16 + l15;
      int kslot = (kk * 4 + lhi) ^ (r & 7);
      a[mi] = *(const bf16x8*)(Hbuf + r * 256 + (kslot << 3));
    }
    #pragma unroll
    for (int ni = 0; ni < 4; ++ni) {
      int n = wc * 64 + ni * 16 + l15;
      b[ni] = *(const bf16x8*)(W2u + n * 256 + kk * 32 + lhi * 8);
    }
    #pragma unroll
    for (int mi = 0; mi < 4; ++mi)
      #pragma unroll
      for (int ni = 0; ni < 4; ++ni)
        acc[mi][ni] = __builtin_amdgcn_mfma_f32_16x16x32_bf16(a[mi], b[ni], acc[mi][ni], 0, 0, 0);
  }

  // ---- epilogue2: store f32 (nontemporal: out is never re-read) ----------
  {
    #pragma unroll
    for (int ni = 0; ni < 4; ++ni) {
      int col = wc * 64 + ni * 16 + l15;
      float bn = b2[col];
      #pragma unroll
      for (int mi = 0; mi < 4; ++mi)
        #pragma unroll
        for (int rg = 0; rg < 4; ++rg) {
          int grow = rb * BM + mi * 16 + lhi * 4 + rg;
          if (grow < M_NODES)
            __builtin_nontemporal_store(acc[mi][ni][rg] + bn,
                                        out + (size_t)grow * 256 + col);
        }
    }
  }
}

// ---------------------------------------------------------------------------
extern "C" void kernel_launch(void* const* d_in, const int* in_sizes, int n_in,
                              void* d_out, int out_size, void* d_ws, size_t ws_size,
                              hipStream_t stream) {
  const float* emb = (const float*)d_in[0];
  const float* W1  = (const float*)d_in[1];
  const float* b1  = (const float*)d_in[2];
  const float* W2  = (const float*)d_in[3];
  const float* b2  = (const float*)d_in[4];
  // d_in[5] = prop_edge_index: unused at ChebConv K=1.
  float* out = (float*)d_out;

  unsigned short* U1 = (unsigned short*)d_ws;   // 65536 ushorts (128KB)
  unsigned short* U2 = U1 + 65536;              // 128KB

  prep_w<<<512, 256, 0, stream>>>(W1, W2, U1, U2);
  cheb_fused<<<NBLK, 256, 0, stream>>>(emb, U1, U2, b1, b2, out);
}

// Round 4
// 86.450 us; speedup vs baseline: 1.5736x; 1.5736x over previous
//
#include <hip/hip_runtime.h>

#define M_NODES 100000
#define BM 64
#define NBLK ((M_NODES + BM - 1) / BM)   // 1563

typedef float  f32x4  __attribute__((ext_vector_type(4)));
typedef short  bf16x8 __attribute__((ext_vector_type(8)));
typedef unsigned short u16x4 __attribute__((ext_vector_type(4)));

__device__ __forceinline__ unsigned short f2bf(float f) {
  union { float f; unsigned int u; } v; v.f = f;
  unsigned int u = v.u;
  return (unsigned short)((u + 0x7FFFu + ((u >> 16) & 1u)) >> 16);  // RNE
}

__device__ __forceinline__ bf16x8 cvt8(f32x4 u0, f32x4 u1) {
  union { unsigned int u[4]; bf16x8 v; } r;
  asm("v_cvt_pk_bf16_f32 %0, %1, %2" : "=v"(r.u[0]) : "v"(u0[0]), "v"(u0[1]));
  asm("v_cvt_pk_bf16_f32 %0, %1, %2" : "=v"(r.u[1]) : "v"(u0[2]), "v"(u0[3]));
  asm("v_cvt_pk_bf16_f32 %0, %1, %2" : "=v"(r.u[2]) : "v"(u1[0]), "v"(u1[1]));
  asm("v_cvt_pk_bf16_f32 %0, %1, %2" : "=v"(r.u[3]) : "v"(u1[2]), "v"(u1[3]));
  return r.v;
}

// slot swizzle for 64B-row LDS tiles (4 slots x 16B per row; bank period = 2
// rows, so fold r>>2 in: 16-lane groups then cover all 32 banks exactly 2x).
__device__ __forceinline__ int swz4(int r, int s) { return s ^ ((r + (r >> 2)) & 3); }

// ---------------------------------------------------------------------------
// prep: W[k][n] f32 -> 8 swizzled bf16 k-tile (BK=32) images, n-major rows.
// img[kt*8192 + n*32 + swz4(n, kl>>3)*8 + (kl&7)] = bf16(W[kt*32+kl][n])
// ---------------------------------------------------------------------------
__global__ void prep_w(const float* __restrict__ W1, const float* __restrict__ W2,
                       unsigned short* __restrict__ R1, unsigned short* __restrict__ R2) {
  int b = blockIdx.x;                       // 128 blocks x 256 threads
  const float* W = (b < 64) ? W1 : W2;
  unsigned short* R = (b < 64) ? R1 : R2;
  int e  = ((b & 63) * 256 + (int)threadIdx.x) * 4;  // [0, 65536)
  int n  = e >> 8;
  int k0 = e & 255;                          // multiple of 4
  u16x4 h;
  #pragma unroll
  for (int i = 0; i < 4; ++i) h[i] = f2bf(W[(k0 + i) * 256 + n]);
  int kt = k0 >> 5, kl = k0 & 31;
  int off = kt * 8192 + n * 32 + (swz4(n, kl >> 3) << 3) + (kl & 7);
  *(u16x4*)(R + off) = h;
}

// ---------------------------------------------------------------------------
// Fused: out[64 x 256] = relu(X@W1+b1)@W2 + b2 per block. 256 thr = 4 waves,
// wave w owns cols [64w,64w+64) (4x4 frags of 16x16x32 bf16).
// LDS 64 KB -> 2 blocks/CU: Hbuf 32KB (A dbuf 2x4KB aliased in during GEMM1)
// + W dbuf 2x16KB (BK=32 tiles via linear global_load_lds of preswizzled
// images). W2 kt0 prefetched during GEMM1 kt7.
// ---------------------------------------------------------------------------
__global__ __launch_bounds__(256, 2)
void cheb_fused(const float* __restrict__ X,
                const unsigned short* __restrict__ W1img,
                const unsigned short* __restrict__ W2img,
                const float* __restrict__ b1,
                const float* __restrict__ b2,
                float* __restrict__ out)
{
  __shared__ unsigned short lds[32768];     // 64 KB
  unsigned short* Hbuf = lds;               // 16384 ushorts (32 KB)
  unsigned short* Ab0  = lds;               // 2048 ushorts (4 KB, inside Hbuf)
  unsigned short* Ab1  = lds + 2048;
  unsigned short* Wb0  = lds + 16384;       // 8192 ushorts (16 KB)
  unsigned short* Wb1  = lds + 24576;

  const int tid  = threadIdx.x;
  const int lane = tid & 63;
  const int l15  = lane & 15;
  const int lhi  = lane >> 4;               // 0..3
  const int w    = tid >> 6;                // 0..3 (N quarter)
  const int rb   = blockIdx.x;

  f32x4 acc[4][4] = {};
  f32x4 u0, u1;                             // X prefetch regs

  auto stageW = [&](const unsigned short* img, int kt, unsigned short* dst) {
    const unsigned short* src = img + kt * 8192;
    #pragma unroll
    for (int it = 0; it < 4; ++it) {
      int chunk = it * 4 + w;               // 16 chunks x 1KB, wave-uniform
      __builtin_amdgcn_global_load_lds(
          (const __attribute__((address_space(1))) unsigned int*)(const void*)(src + chunk * 512 + lane * 8),
          (__attribute__((address_space(3))) unsigned int*)(void*)(dst + chunk * 512),
          16, 0, 0);
    }
  };
  auto loadA = [&](int kt) {                // issue early (T14): X f32 -> regs
    int r = tid >> 2;
    int grow = rb * BM + r;
    u0 = f32x4{0.f, 0.f, 0.f, 0.f}; u1 = u0;
    if (grow < M_NODES) {
      const float* p = X + (size_t)grow * 256 + kt * 32 + (tid & 3) * 8;
      u0 = *(const f32x4*)p;
      u1 = *(const f32x4*)(p + 4);
    }
  };
  auto writeA = [&](unsigned short* dst) {  // write late: cvt + swizzled b128
    int r = tid >> 2;
    *(bf16x8*)(dst + r * 32 + (swz4(r, tid & 3) << 3)) = cvt8(u0, u1);
  };
  auto computeA = [&](const unsigned short* A, const unsigned short* B) {
    bf16x8 a[4], b[4];
    #pragma unroll
    for (int mi = 0; mi < 4; ++mi) {
      int r = mi * 16 + l15;
      a[mi] = *(const bf16x8*)(A + r * 32 + (swz4(r, lhi) << 3));
    }
    #pragma unroll
    for (int ni = 0; ni < 4; ++ni) {
      int n = w * 64 + ni * 16 + l15;
      b[ni] = *(const bf16x8*)(B + n * 32 + (swz4(n, lhi) << 3));
    }
    #pragma unroll
    for (int mi = 0; mi < 4; ++mi)
      #pragma unroll
      for (int ni = 0; ni < 4; ++ni)
        acc[mi][ni] = __builtin_amdgcn_mfma_f32_16x16x32_bf16(a[mi], b[ni], acc[mi][ni], 0, 0, 0);
  };
  auto computeH = [&](int kt, const unsigned short* B) {
    bf16x8 a[4], b[4];
    #pragma unroll
    for (int mi = 0; mi < 4; ++mi) {
      int r = mi * 16 + l15;
      int ks = (kt * 4 + lhi) ^ (r & 7);    // Hbuf rows are 512B: 3-bit swizzle
      a[mi] = *(const bf16x8*)(Hbuf + r * 256 + (ks << 3));
    }
    #pragma unroll
    for (int ni = 0; ni < 4; ++ni) {
      int n = w * 64 + ni * 16 + l15;
      b[ni] = *(const bf16x8*)(B + n * 32 + (swz4(n, lhi) << 3));
    }
    #pragma unroll
    for (int mi = 0; mi < 4; ++mi)
      #pragma unroll
      for (int ni = 0; ni < 4; ++ni)
        acc[mi][ni] = __builtin_amdgcn_mfma_f32_16x16x32_bf16(a[mi], b[ni], acc[mi][ni], 0, 0, 0);
  };

  // ---- GEMM1: H = relu(X @ W1 + b1), 8 k-steps of 32 ---------------------
  loadA(0);
  stageW(W1img, 0, Wb0);
  writeA(Ab0);
  __syncthreads();

  #pragma unroll
  for (int kt = 0; kt < 8; ++kt) {
    unsigned short* Acur = (kt & 1) ? Ab1 : Ab0;
    unsigned short* Anxt = (kt & 1) ? Ab0 : Ab1;
    unsigned short* Wcur = (kt & 1) ? Wb1 : Wb0;
    unsigned short* Wnxt = (kt & 1) ? Wb0 : Wb1;
    if (kt < 7) {
      loadA(kt + 1);
      stageW(W1img, kt + 1, Wnxt);
    } else {
      stageW(W2img, 0, Wnxt);               // prefetch GEMM2 kt0 (lands in Wb0)
    }
    computeA(Acur, Wcur);
    if (kt < 7) writeA(Anxt);
    __syncthreads();
  }

  // ---- epilogue1: bias + relu + bf16 -> Hbuf (3-bit XOR swizzle) ---------
  {
    #pragma unroll
    for (int ni = 0; ni < 4; ++ni) {
      int k = w * 64 + ni * 16 + l15;
      float bn = b1[k];
      #pragma unroll
      for (int mi = 0; mi < 4; ++mi)
        #pragma unroll
        for (int rg = 0; rg < 4; ++rg) {
          int r = mi * 16 + lhi * 4 + rg;
          float v = fmaxf(acc[mi][ni][rg] + bn, 0.f);
          Hbuf[r * 256 + (((k >> 3) ^ (r & 7)) << 3) + (k & 7)] = f2bf(v);
          acc[mi][ni][rg] = 0.f;
        }
    }
  }
  __syncthreads();

  // ---- GEMM2: out = H @ W2 + b2 ------------------------------------------
  #pragma unroll
  for (int kt = 0; kt < 8; ++kt) {
    unsigned short* Wcur = (kt & 1) ? Wb1 : Wb0;
    unsigned short* Wnxt = (kt & 1) ? Wb0 : Wb1;
    if (kt < 7) stageW(W2img, kt + 1, Wnxt);
    computeH(kt, Wcur);
    if (kt < 7) __syncthreads();
  }

  // ---- epilogue2: +b2, nontemporal f32 stores ----------------------------
  {
    #pragma unroll
    for (int ni = 0; ni < 4; ++ni) {
      int col = w * 64 + ni * 16 + l15;
      float bn = b2[col];
      #pragma unroll
      for (int mi = 0; mi < 4; ++mi)
        #pragma unroll
        for (int rg = 0; rg < 4; ++rg) {
          int grow = rb * BM + mi * 16 + lhi * 4 + rg;
          if (grow < M_NODES)
            __builtin_nontemporal_store(acc[mi][ni][rg] + bn,
                                        out + (size_t)grow * 256 + col);
        }
    }
  }
}

// ---------------------------------------------------------------------------
extern "C" void kernel_launch(void* const* d_in, const int* in_sizes, int n_in,
                              void* d_out, int out_size, void* d_ws, size_t ws_size,
                              hipStream_t stream) {
  const float* emb = (const float*)d_in[0];
  const float* W1  = (const float*)d_in[1];
  const float* b1  = (const float*)d_in[2];
  const float* W2  = (const float*)d_in[3];
  const float* b2  = (const float*)d_in[4];
  // d_in[5] = prop_edge_index: unused at ChebConv K=1.
  float* out = (float*)d_out;

  unsigned short* U1 = (unsigned short*)d_ws;   // 65536 ushorts (128KB)
  unsigned short* U2 = U1 + 65536;              // 128KB

  prep_w<<<128, 256, 0, stream>>>(W1, W2, U1, U2);
  cheb_fused<<<NBLK, 256, 0, stream>>>(emb, U1, U2, b1, b2, out);
}

// Round 5
// 78.463 us; speedup vs baseline: 1.7337x; 1.1018x over previous
//
#include <hip/hip_runtime.h>

#define M_NODES 100000
#define BM 64
#define NT ((M_NODES + BM - 1) / BM)   // 1563 row-tiles
#define GRID 256                        // persistent: 1 block/CU

typedef float  f32x4  __attribute__((ext_vector_type(4)));
typedef short  bf16x8 __attribute__((ext_vector_type(8)));

__device__ __forceinline__ unsigned short f2bf(float f) {
  union { float f; unsigned int u; } v; v.f = f;
  unsigned int u = v.u;
  return (unsigned short)((u + 0x7FFFu + ((u >> 16) & 1u)) >> 16);  // RNE
}

__device__ __forceinline__ bf16x8 cvt8(f32x4 u0, f32x4 u1) {
  union { unsigned int u[4]; bf16x8 v; } r;
  asm("v_cvt_pk_bf16_f32 %0, %1, %2" : "=v"(r.u[0]) : "v"(u0[0]), "v"(u0[1]));
  asm("v_cvt_pk_bf16_f32 %0, %1, %2" : "=v"(r.u[1]) : "v"(u0[2]), "v"(u0[3]));
  asm("v_cvt_pk_bf16_f32 %0, %1, %2" : "=v"(r.u[2]) : "v"(u1[0]), "v"(u1[1]));
  asm("v_cvt_pk_bf16_f32 %0, %1, %2" : "=v"(r.u[3]) : "v"(u1[2]), "v"(u1[3]));
  return r.v;
}

// raw barrier: lgkm drain only — global (vmcnt) prefetch stays in flight
#define BARRIER() do { asm volatile("s_waitcnt lgkmcnt(0)" ::: "memory"); \
                       __builtin_amdgcn_s_barrier(); } while (0)

// ---------------------------------------------------------------------------
// prep: W[k][n] f32 -> Wu[n*256+k] bf16 (transposed, B-frag-ready, L2-hot)
// ---------------------------------------------------------------------------
__global__ void prep_w(const float* __restrict__ W1, const float* __restrict__ W2,
                       unsigned short* __restrict__ U1, unsigned short* __restrict__ U2) {
  int b = blockIdx.x;                       // 512 blocks x 256 threads
  const float* W = (b < 256) ? W1 : W2;
  unsigned short* U = (b < 256) ? U1 : U2;
  int n = b & 255, k = threadIdx.x;
  U[n * 256 + k] = f2bf(W[k * 256 + n]);
}

// ---------------------------------------------------------------------------
// Persistent fused kernel. 256 blocks x 512 threads (8 waves), 1 block/CU.
// Wave w owns output cols [32w, 32w+32): B-frags of W1 AND W2 in VGPRs
// (2ni x 8kk x 4regs x 2mats = 128 VGPR), loaded once per block.
// Per tile (64 rows): GEMM1 from LDS Abuf -> relu/bias -> Hbuf -> barrier ->
// GEMM2 -> stores -> cvt next A (reg-prefetched 2 tiles ahead) -> barrier.
// Barriers never drain vmcnt: X stream stays outstanding => HBM-bound pace.
// LDS 96KB: Ab0/Ab1 32KB each + Hbuf 32KB. 3-bit XOR slot swizzle (R2-proven).
// ---------------------------------------------------------------------------
__global__ __launch_bounds__(512, 2)
void cheb_fused(const float* __restrict__ X,
                const unsigned short* __restrict__ W1u,
                const unsigned short* __restrict__ W2u,
                const float* __restrict__ b1,
                const float* __restrict__ b2,
                float* __restrict__ out)
{
  __shared__ unsigned short lds[49152];     // 96 KB
  unsigned short* Ab0  = lds;               // 16384 ushorts (32 KB)
  unsigned short* Ab1  = lds + 16384;
  unsigned short* Hbuf = lds + 32768;

  const int tid  = threadIdx.x;
  const int lane = tid & 63;
  const int l15  = lane & 15;
  const int lhi  = lane >> 4;               // 0..3
  const int w    = tid >> 6;                // 0..7
  const int nc0  = w * 32;                  // wave's output-col base

  // ---- W fragments -> registers (once per block; W images are L2-hot) ----
  bf16x8 Wf1[2][8], Wf2[2][8];
  #pragma unroll
  for (int ni = 0; ni < 2; ++ni) {
    int n = nc0 + ni * 16 + l15;
    #pragma unroll
    for (int kk = 0; kk < 8; ++kk) {
      Wf1[ni][kk] = *(const bf16x8*)(W1u + n * 256 + kk * 32 + lhi * 8);
      Wf2[ni][kk] = *(const bf16x8*)(W2u + n * 256 + kk * 32 + lhi * 8);
    }
  }
  float bn1[2] = { b1[nc0 + l15], b1[nc0 + 16 + l15] };
  float bn2[2] = { b2[nc0 + l15], b2[nc0 + 16 + l15] };

  f32x4 acc[4][2] = {};
  f32x4 xr[4][2];                           // X prefetch (one tile, 32 regs)

  auto loadX = [&](int t) {                 // issue 8 x 16B coalesced / thread
    #pragma unroll
    for (int i = 0; i < 4; ++i) {
      int g = i * 512 + tid;                // 2048 granules of 32B
      int r = g >> 5, c8 = g & 31;
      int grow = t * BM + r;
      f32x4 a = {0.f, 0.f, 0.f, 0.f}, b = a;
      if (grow < M_NODES) {
        const float* p = X + (size_t)grow * 256 + c8 * 8;
        a = *(const f32x4*)p;
        b = *(const f32x4*)(p + 4);
      }
      xr[i][0] = a; xr[i][1] = b;
    }
  };
  auto cvtX = [&](unsigned short* dst) {    // cvt + swizzled b128 LDS write
    #pragma unroll
    for (int i = 0; i < 4; ++i) {
      int g = i * 512 + tid;
      int r = g >> 5, c8 = g & 31;
      *(bf16x8*)(dst + r * 256 + (((c8 & 7) ^ (r & 7)) << 3) + ((c8 >> 3) << 6)
                 - ((c8 >> 3) << 6) + ((c8 ^ (r & 7)) << 3) - (((c8 & 7) ^ (r & 7)) << 3))
          = cvt8(xr[i][0], xr[i][1]);
    }
  };
  auto gemm = [&](const unsigned short* A, bf16x8 (&Wf)[2][8]) {
    #pragma unroll
    for (int kk = 0; kk < 8; ++kk) {
      bf16x8 a[4];
      #pragma unroll
      for (int mi = 0; mi < 4; ++mi) {
        int r = mi * 16 + l15;
        int s = (kk * 4 + lhi) ^ (r & 7);
        a[mi] = *(const bf16x8*)(A + r * 256 + (s << 3));
      }
      #pragma unroll
      for (int mi = 0; mi < 4; ++mi)
        #pragma unroll
        for (int ni = 0; ni < 2; ++ni)
          acc[mi][ni] = __builtin_amdgcn_mfma_f32_16x16x32_bf16(a[mi], Wf[ni][kk], acc[mi][ni], 0, 0, 0);
    }
  };

  // ---- prologue -----------------------------------------------------------
  const int t0 = blockIdx.x;
  loadX(t0);
  cvtX(Ab0);                                 // waits only its own loads
  loadX(t0 + GRID);                          // tile 2 in flight across barrier
  BARRIER();

  int it = 0;
  for (int t = t0; t < NT; t += GRID, ++it) {
    unsigned short* Acur = (it & 1) ? Ab1 : Ab0;
    unsigned short* Anxt = (it & 1) ? Ab0 : Ab1;

    // GEMM1: acc = A x W1
    gemm(Acur, Wf1);

    // epilogue1: bias + relu + bf16 -> Hbuf (swizzled), reset acc
    #pragma unroll
    for (int ni = 0; ni < 2; ++ni) {
      int k = nc0 + ni * 16 + l15;
      #pragma unroll
      for (int mi = 0; mi < 4; ++mi)
        #pragma unroll
        for (int rg = 0; rg < 4; ++rg) {
          int r = mi * 16 + lhi * 4 + rg;
          float v = fmaxf(acc[mi][ni][rg] + bn1[ni], 0.f);
          Hbuf[r * 256 + (((k >> 3) ^ (r & 7)) << 3) + (k & 7)] = f2bf(v);
          acc[mi][ni][rg] = 0.f;
        }
    }
    BARRIER();                               // Hbuf ready (lgkm only)

    // GEMM2: acc = H x W2
    gemm(Hbuf, Wf2);

    // epilogue2: +b2, nontemporal stores, reset acc
    #pragma unroll
    for (int mi = 0; mi < 4; ++mi)
      #pragma unroll
      for (int rg = 0; rg < 4; ++rg) {
        int grow = t * BM + mi * 16 + lhi * 4 + rg;
        #pragma unroll
        for (int ni = 0; ni < 2; ++ni) {
          float v = acc[mi][ni][rg] + bn2[ni];
          acc[mi][ni][rg] = 0.f;
          if (grow < M_NODES)
            __builtin_nontemporal_store(v, out + (size_t)grow * 256 + nc0 + ni * 16 + l15);
        }
      }

    // stage next A tile; issue loads 2 tiles ahead (stay in flight over barrier)
    if (t + GRID < NT) {
      cvtX(Anxt);                            // waits xr loads (issued 1 iter ago)
      loadX(t + 2 * GRID);
    }
    BARRIER();                               // Anxt ready / Hbuf consumed
  }
}

// ---------------------------------------------------------------------------
extern "C" void kernel_launch(void* const* d_in, const int* in_sizes, int n_in,
                              void* d_out, int out_size, void* d_ws, size_t ws_size,
                              hipStream_t stream) {
  const float* emb = (const float*)d_in[0];
  const float* W1  = (const float*)d_in[1];
  const float* b1  = (const float*)d_in[2];
  const float* W2  = (const float*)d_in[3];
  const float* b2  = (const float*)d_in[4];
  // d_in[5] = prop_edge_index: unused at ChebConv K=1.
  float* out = (float*)d_out;

  unsigned short* U1 = (unsigned short*)d_ws;   // 65536 ushorts (128KB)
  unsigned short* U2 = U1 + 65536;              // 128KB

  prep_w<<<512, 256, 0, stream>>>(W1, W2, U1, U2);
  cheb_fused<<<GRID, 512, 0, stream>>>(emb, U1, U2, b1, b2, out);
}